// Round 11
// baseline (48552.481 us; speedup 1.0000x reference)
//
#include <hip/hip_runtime.h>

#define T_STEPS 4096
#define HD 2048
#define G4 8192
#define NWG 256
#define NTH 512
#define HSENT2 0xFF80FF80u

#define HB_OFF  131072                    // weights 128 KB, then h spans 4 KB
#define P_OFF   (131072 + 4096)           // partials: 2 x (8 waves x 32) f32 = 2 KB
#define SMEM_BYTES (131072 + 4096 + 2048)

typedef __attribute__((ext_vector_type(8))) short bf16x8;
typedef __attribute__((ext_vector_type(4))) float f32x4;
typedef __attribute__((ext_vector_type(8))) unsigned short u16x8;
typedef __attribute__((ext_vector_type(2))) unsigned int u32x2;

static __device__ __forceinline__ unsigned short f2bf(float f){
  union { float f; unsigned int u; } v; v.f = f;
  unsigned int r = (v.u + 0x7fffu + ((v.u >> 16) & 1u)) >> 16;
  return (unsigned short)r;
}
static __device__ __forceinline__ float bf2f(unsigned short s){
  union { unsigned int u; float f; } v; v.u = ((unsigned int)s) << 16;
  return v.f;
}

// ---- memory-side atomic transport (R11) ----
// Publish: global_atomic_swap, NO return (fire-and-forget) — executes at the
// memory-side L3 atomic unit in one-way flight; cannot linger in a lazy
// store/WC path (the R2-R10 invariance suspect).
static __device__ __forceinline__ void pub_atomic(unsigned int* p, unsigned int v){
  asm volatile("global_atomic_swap %0, %1, off sc1" :: "v"(p), "v"(v) : "memory");
}
// Poll: global_atomic_or_x2 with 0, sc0 = return old — an RMW that reads the
// CURRENT L3 value (or|0 writes back unchanged; atomicity vs the 4B swaps
// guarantees each half is either sentinel or final data).
static __device__ __forceinline__ u32x2 poll_atomic(const unsigned int* p,
                                                    unsigned long long zero){
  unsigned long long r;
  asm volatile("global_atomic_or_x2 %0, %1, %2, off sc0 sc1\n\ts_waitcnt vmcnt(0)"
               : "=v"(r) : "v"(p), "v"(zero) : "memory");
  u32x2 o; o[0] = (unsigned)r; o[1] = (unsigned)(r >> 32);
  return o;
}

// ---------------- init: bias fuse + h0 zeros + sentinel rows (bf16) ----------------
__global__ void init_kernel(const float* __restrict__ b_ih, const float* __restrict__ b_hh,
                            float* __restrict__ bias, unsigned int* __restrict__ Hb32){
  int i = blockIdx.x*blockDim.x + threadIdx.x;
  int stride = gridDim.x*blockDim.x;
  const int HB_U32 = (T_STEPS+1)*HD/2;
  const int NTOT = G4 + HB_U32;
  for (int idx = i; idx < NTOT; idx += stride){
    if (idx < G4) bias[idx] = b_ih[idx] + b_hh[idx];
    else {
      int j = idx - G4;
      Hb32[j] = (j < HD/2) ? 0u : HSENT2;   // row 0 = bf16 zeros, rest sentinel
    }
  }
}

// ---------------- phase 1: XP = x @ W_ih^T + (b_ih+b_hh), bf16 out ----------------
__global__ __launch_bounds__(256) void gemm_xp(const float* __restrict__ X,
                                               const float* __restrict__ W,
                                               const float* __restrict__ bias,
                                               unsigned short* __restrict__ XP){
  __shared__ __align__(16) unsigned short As[128][40];
  __shared__ __align__(16) unsigned short Bs[128][40];
  const int tid = threadIdx.x;
  const int bx = blockIdx.x & 63;
  const int by = blockIdx.x >> 6;
  const int row0 = by*128, col0 = bx*128;
  const int l = tid & 63, w = tid >> 6;
  const int wrow = (w>>1)*64, wcol = (w&1)*64;
  const int lr = l & 15, lk = l >> 4;

  f32x4 acc[4][4];
  #pragma unroll
  for (int mi=0; mi<4; mi++)
    #pragma unroll
    for (int ni=0; ni<4; ni++)
      acc[mi][ni] = (f32x4){0.f,0.f,0.f,0.f};

  const int sr = tid >> 1;
  const int sh = (tid & 1) * 16;
  const float* xb = X + (size_t)(row0+sr)*2048 + sh;
  const float* wb = W + (size_t)(col0+sr)*2048 + sh;

  for (int k0 = 0; k0 < 2048; k0 += 32){
    __syncthreads();
    u16x8 va[2], vb[2];
    #pragma unroll
    for (int q=0; q<2; q++){
      float4 u = *(const float4*)(xb + k0 + q*8);
      float4 v = *(const float4*)(xb + k0 + q*8 + 4);
      u16x8 t;
      t[0]=f2bf(u.x); t[1]=f2bf(u.y); t[2]=f2bf(u.z); t[3]=f2bf(u.w);
      t[4]=f2bf(v.x); t[5]=f2bf(v.y); t[6]=f2bf(v.z); t[7]=f2bf(v.w);
      va[q]=t;
      float4 p = *(const float4*)(wb + k0 + q*8);
      float4 r = *(const float4*)(wb + k0 + q*8 + 4);
      u16x8 s;
      s[0]=f2bf(p.x); s[1]=f2bf(p.y); s[2]=f2bf(p.z); s[3]=f2bf(p.w);
      s[4]=f2bf(r.x); s[5]=f2bf(r.y); s[6]=f2bf(r.z); s[7]=f2bf(r.w);
      vb[q]=s;
    }
    *(u16x8*)&As[sr][sh]   = va[0];
    *(u16x8*)&As[sr][sh+8] = va[1];
    *(u16x8*)&Bs[sr][sh]   = vb[0];
    *(u16x8*)&Bs[sr][sh+8] = vb[1];
    __syncthreads();

    bf16x8 af[4], bfr[4];
    #pragma unroll
    for (int mi=0; mi<4; mi++) af[mi]  = *(const bf16x8*)&As[wrow+mi*16+lr][lk*8];
    #pragma unroll
    for (int ni=0; ni<4; ni++) bfr[ni] = *(const bf16x8*)&Bs[wcol+ni*16+lr][lk*8];
    #pragma unroll
    for (int mi=0; mi<4; mi++)
      #pragma unroll
      for (int ni=0; ni<4; ni++)
        acc[mi][ni] = __builtin_amdgcn_mfma_f32_16x16x32_bf16(af[mi], bfr[ni], acc[mi][ni], 0,0,0);
  }

  #pragma unroll
  for (int ni=0; ni<4; ni++){
    const int jc = col0 + wcol + ni*16 + lr;
    const float bv = bias[jc];
    #pragma unroll
    for (int mi=0; mi<4; mi++){
      const int tr0 = row0 + wrow + mi*16 + lk*4;
      #pragma unroll
      for (int r=0; r<4; r++)
        XP[(size_t)(tr0+r)*G4 + jc] = f2bf(acc[mi][ni][r] + bv);
    }
  }
}

// ---------------- phase 2: persistent LSTM recurrence (MFMA, 8 waves) ----------------
// R8 structure; ONLY the transport changed: publish = memory-side atomic_swap
// (fire-and-forget), poll = atomic_or_x2(0) with return (fresh L3 read each
// round). 256 WGs x 512 thr. WG g owns h-dims [8g,8g+8) = 32 gate rows.
// Wave w: polls own 512B span of h, LDS-stages it, 16 MFMAs with LDS-resident
// pre-swizzled B-frag weights, partial write, ONE barrier, wave 0 reduces +
// parallel-lane cell + 4-lane atomic publish.
__global__ __launch_bounds__(NTH, 1) void recur(const unsigned short* __restrict__ XP,
                                                const float* __restrict__ Whh,
                                                unsigned short* __restrict__ Hbuf){
  extern __shared__ char smem[];
  char* hb = smem + HB_OFF;
  const int g = blockIdx.x;
  const int tid = threadIdx.x;
  const int l = tid & 63, w = tid >> 6;

  // ---- stage weights as pre-swizzled MFMA B-fragments (128 KB LDS) ----
  #pragma unroll
  for (int n=0; n<2; n++)
    #pragma unroll
    for (int kt=0; kt<8; kt++){
      const int rr = n*16 + (l & 15);
      const size_t jrow = (size_t)(rr>>3)*HD + (size_t)g*8 + (rr&7);
      const int k = w*256 + kt*32 + (l>>4)*8;
      const float* wp = Whh + jrow*HD + k;
      float4 fa = *(const float4*)wp;
      float4 fb = *(const float4*)(wp + 4);
      uint4 pk;
      pk.x = ((unsigned)f2bf(fa.y)<<16) | f2bf(fa.x);
      pk.y = ((unsigned)f2bf(fa.w)<<16) | f2bf(fa.z);
      pk.z = ((unsigned)f2bf(fb.y)<<16) | f2bf(fb.x);
      pk.w = ((unsigned)f2bf(fb.w)<<16) | f2bf(fb.z);
      *(uint4*)(smem + (size_t)(((w*16 + n*8 + kt)*64 + l)*16)) = pk;
    }
  __syncthreads();

  float c_reg = 0.f;     // cell state (wave 0, lanes 0..7)
  float xpv = 0.f;       // gate preact input (wave 0, lanes 0..31)
  if (w == 0 && l < 32)
    xpv = bf2f(XP[(size_t)(l>>3)*HD + (size_t)g*8 + (l&7)]);

  for (int t=0; t<T_STEPS; ++t){
    // ---- poll own span of h[t-1] (row t; row 0 = zeros) via memory-side atomic ----
    u32x2 hv;
    {
      const unsigned int* hp = (const unsigned int*)(Hbuf + (size_t)t*HD) + w*128 + l*2;
      do { hv = poll_atomic(hp, 0ull); }
      while (hv[0] == HSENT2 || hv[1] == HSENT2);
    }
    *(u32x2*)(hb + w*512 + l*8) = hv;

    // A-fragments: broadcast h (same addr within each 16-lane group)
    bf16x8 af[8];
    #pragma unroll
    for (int kt=0; kt<8; kt++)
      af[kt] = *(const bf16x8*)(hb + w*512 + kt*64 + (l>>4)*16);

    f32x4 acc0 = (f32x4){0.f,0.f,0.f,0.f};
    f32x4 acc1 = (f32x4){0.f,0.f,0.f,0.f};
    #pragma unroll
    for (int kt=0; kt<8; kt++){
      bf16x8 b0 = *(const bf16x8*)(smem + (size_t)(((w*16 +     kt)*64 + l)*16));
      bf16x8 b1 = *(const bf16x8*)(smem + (size_t)(((w*16 + 8 + kt)*64 + l)*16));
      acc0 = __builtin_amdgcn_mfma_f32_16x16x32_bf16(af[kt], b0, acc0, 0,0,0);
      acc1 = __builtin_amdgcn_mfma_f32_16x16x32_bf16(af[kt], b1, acc1, 0,0,0);
    }
    // partials: [wave][row] layout (conflict-free), parity double-buffered
    float* part = (float*)(smem + P_OFF) + (t&1)*256;
    if (l < 16){
      part[w*32 + l]      = acc0[0];
      part[w*32 + 16 + l] = acc1[0];
    }
    __syncthreads();

    // wave 0: reduce + parallel-lane cell + atomic publish
    if (w == 0){
      __builtin_amdgcn_s_setprio(1);
      float act = 0.f;
      if (l < 32){
        float tot = xpv;
        #pragma unroll
        for (int q=0; q<8; q++) tot += part[q*32 + l];
        const bool isg = ((l>>3) == 2);
        float z = __expf(isg ? -2.f*tot : -tot);
        float s = 1.f/(1.f + z);
        act = isg ? 2.f*s - 1.f : s;    // tanh via sigmoid identity for g-gate
      }
      float fv = __shfl_down(act, 8, 64);
      float gv = __shfl_down(act, 16, 64);
      float ov = __shfl_down(act, 24, 64);
      if (l < 8){
        c_reg = fv*c_reg + act*gv;      // act = i-gate on lanes 0..7
        float e2c = __expf(-2.f*c_reg);
        float th = (1.f - e2c)/(1.f + e2c);
        unsigned v = f2bf(ov*th);
        unsigned p1 = (unsigned)__shfl_xor((int)v, 1, 64);
        unsigned word = (v & 0xFFFFu) | (p1 << 16);   // valid on even lanes
        if ((l & 1) == 0){
          unsigned int* dst = (unsigned int*)(Hbuf + (size_t)(t+1)*HD + (size_t)g*8) + (l>>1);
          pub_atomic(dst, word);
        }
      }
      __builtin_amdgcn_s_setprio(0);
      // preload next step's XP (off critical path)
      if (l < 32){
        const int tn = (t+1 < T_STEPS) ? t+1 : t;
        xpv = bf2f(XP[(size_t)tn*G4 + (size_t)(l>>3)*HD + (size_t)g*8 + (l&7)]);
      }
    }
  }
}

// ---------------- phase 3: y[t] = h_t . W_out + b_out (h is bf16) ----------------
__global__ __launch_bounds__(256) void out_gemv(const unsigned short* __restrict__ Hbuf,
                                                const float* __restrict__ Wout,
                                                const float* __restrict__ bout,
                                                float* __restrict__ y){
  const int t = blockIdx.x;
  const int tid = threadIdx.x;
  u16x8 hv = *(const u16x8*)(Hbuf + (size_t)(t+1)*HD + tid*8);
  float4 w0 = *(const float4*)(Wout + tid*8);
  float4 w1 = *(const float4*)(Wout + tid*8 + 4);
  float s = bf2f(hv[0])*w0.x + bf2f(hv[1])*w0.y + bf2f(hv[2])*w0.z + bf2f(hv[3])*w0.w
          + bf2f(hv[4])*w1.x + bf2f(hv[5])*w1.y + bf2f(hv[6])*w1.z + bf2f(hv[7])*w1.w;
  #pragma unroll
  for (int off=32; off; off>>=1) s += __shfl_xor(s, off, 64);
  __shared__ float ps[4];
  if ((tid & 63) == 0) ps[tid>>6] = s;
  __syncthreads();
  if (tid == 0) y[t] = ps[0]+ps[1]+ps[2]+ps[3] + bout[0];
}

extern "C" void kernel_launch(void* const* d_in, const int* in_sizes, int n_in,
                              void* d_out, int out_size, void* d_ws, size_t ws_size,
                              hipStream_t stream) {
  const float* x    = (const float*)d_in[0];
  const float* Wih  = (const float*)d_in[1];
  const float* Whh  = (const float*)d_in[2];
  const float* b_ih = (const float*)d_in[3];
  const float* b_hh = (const float*)d_in[4];
  const float* Wout = (const float*)d_in[5];
  const float* bout = (const float*)d_in[6];
  float* y = (float*)d_out;

  char* ws = (char*)d_ws;
  unsigned short* XP   = (unsigned short*)(ws);               // 4096*8192*2   = 67108864
  unsigned short* Hbuf = (unsigned short*)(ws + 67108864);    // 4097*2048*2   = 16781312
  float* bias          = (float*)(ws + 83890176);             // 8192*4        = 32768

  init_kernel<<<2048, 256, 0, stream>>>(b_ih, b_hh, bias, (unsigned int*)Hbuf);
  gemm_xp<<<2048, 256, 0, stream>>>(x, Wih, bias, XP);

  hipFuncSetAttribute((const void*)recur,
                      hipFuncAttributeMaxDynamicSharedMemorySize, SMEM_BYTES);
  void* args[] = {(void*)&XP, (void*)&Whh, (void*)&Hbuf};
  hipLaunchCooperativeKernel((void*)recur, dim3(NWG), dim3(NTH), args,
                             SMEM_BYTES, stream);

  out_gemv<<<T_STEPS, 256, 0, stream>>>(Hbuf, Wout, bout, y);
}

// Round 12
// 11240.564 us; speedup vs baseline: 4.3194x; 4.3194x over previous
//
#include <hip/hip_runtime.h>

#define T_STEPS 4096
#define HD 2048
#define G4 8192
#define NWG 256
#define NTH 512
#define HSENT2 0xFF80FF80u

#define HB_OFF  131072                    // weights 128 KB, then h spans 4 KB
#define P_OFF   (131072 + 4096)           // partials: 2 x (8 waves x 32) f32 = 2 KB
#define SMEM_BYTES (131072 + 4096 + 2048)

typedef __attribute__((ext_vector_type(8))) short bf16x8;
typedef __attribute__((ext_vector_type(4))) float f32x4;
typedef __attribute__((ext_vector_type(8))) unsigned short u16x8;
typedef __attribute__((ext_vector_type(2))) unsigned int u32x2;

static __device__ __forceinline__ unsigned short f2bf(float f){
  union { float f; unsigned int u; } v; v.f = f;
  unsigned int r = (v.u + 0x7fffu + ((v.u >> 16) & 1u)) >> 16;
  return (unsigned short)r;
}
static __device__ __forceinline__ float bf2f(unsigned short s){
  union { unsigned int u; float f; } v; v.u = ((unsigned int)s) << 16;
  return v.f;
}

// POLL: plain device-scope (sc1) 8B load — bypasses L1/L2, reads L3 directly.
// Read-only, MSHR-merged across same-line pollers (R8-proven cheap).
static __device__ __forceinline__ u32x2 ld2_dev(const unsigned int* p){
  u32x2 r;
  asm volatile("global_load_dwordx2 %0, %1, off sc1\n\ts_waitcnt vmcnt(0)"
               : "=v"(r) : "v"(p) : "memory");
  return r;
}
// PUBLISH: memory-side atomic swap, NO return (fire-and-forget). Executes at
// the L3 atomic unit -> commits at the coherence point in one-way flight;
// cannot linger in a lazy store/WC drain path. R10 arithmetic showed store-
// issue -> remote-visible ~= 5500 cyc (~7 poll rounds); this is the
// single-variable test of that write-visibility theory (R11 poisoned it by
// also making the POLL an atomic RMW -> 8.6 GB of writes + serialization).
static __device__ __forceinline__ void pub_atomic(unsigned int* p, unsigned int v){
  asm volatile("global_atomic_swap %0, %1, off sc1" :: "v"(p), "v"(v) : "memory");
}

// ---------------- init: bias fuse + h0 zeros + sentinel rows (bf16) ----------------
__global__ void init_kernel(const float* __restrict__ b_ih, const float* __restrict__ b_hh,
                            float* __restrict__ bias, unsigned int* __restrict__ Hb32){
  int i = blockIdx.x*blockDim.x + threadIdx.x;
  int stride = gridDim.x*blockDim.x;
  const int HB_U32 = (T_STEPS+1)*HD/2;
  const int NTOT = G4 + HB_U32;
  for (int idx = i; idx < NTOT; idx += stride){
    if (idx < G4) bias[idx] = b_ih[idx] + b_hh[idx];
    else {
      int j = idx - G4;
      Hb32[j] = (j < HD/2) ? 0u : HSENT2;   // row 0 = bf16 zeros, rest sentinel
    }
  }
}

// ---------------- phase 1: XP = x @ W_ih^T + (b_ih+b_hh), bf16 out ----------------
__global__ __launch_bounds__(256) void gemm_xp(const float* __restrict__ X,
                                               const float* __restrict__ W,
                                               const float* __restrict__ bias,
                                               unsigned short* __restrict__ XP){
  __shared__ __align__(16) unsigned short As[128][40];
  __shared__ __align__(16) unsigned short Bs[128][40];
  const int tid = threadIdx.x;
  const int bx = blockIdx.x & 63;
  const int by = blockIdx.x >> 6;
  const int row0 = by*128, col0 = bx*128;
  const int l = tid & 63, w = tid >> 6;
  const int wrow = (w>>1)*64, wcol = (w&1)*64;
  const int lr = l & 15, lk = l >> 4;

  f32x4 acc[4][4];
  #pragma unroll
  for (int mi=0; mi<4; mi++)
    #pragma unroll
    for (int ni=0; ni<4; ni++)
      acc[mi][ni] = (f32x4){0.f,0.f,0.f,0.f};

  const int sr = tid >> 1;
  const int sh = (tid & 1) * 16;
  const float* xb = X + (size_t)(row0+sr)*2048 + sh;
  const float* wb = W + (size_t)(col0+sr)*2048 + sh;

  for (int k0 = 0; k0 < 2048; k0 += 32){
    __syncthreads();
    u16x8 va[2], vb[2];
    #pragma unroll
    for (int q=0; q<2; q++){
      float4 u = *(const float4*)(xb + k0 + q*8);
      float4 v = *(const float4*)(xb + k0 + q*8 + 4);
      u16x8 t;
      t[0]=f2bf(u.x); t[1]=f2bf(u.y); t[2]=f2bf(u.z); t[3]=f2bf(u.w);
      t[4]=f2bf(v.x); t[5]=f2bf(v.y); t[6]=f2bf(v.z); t[7]=f2bf(v.w);
      va[q]=t;
      float4 p = *(const float4*)(wb + k0 + q*8);
      float4 r = *(const float4*)(wb + k0 + q*8 + 4);
      u16x8 s;
      s[0]=f2bf(p.x); s[1]=f2bf(p.y); s[2]=f2bf(p.z); s[3]=f2bf(p.w);
      s[4]=f2bf(r.x); s[5]=f2bf(r.y); s[6]=f2bf(r.z); s[7]=f2bf(r.w);
      vb[q]=s;
    }
    *(u16x8*)&As[sr][sh]   = va[0];
    *(u16x8*)&As[sr][sh+8] = va[1];
    *(u16x8*)&Bs[sr][sh]   = vb[0];
    *(u16x8*)&Bs[sr][sh+8] = vb[1];
    __syncthreads();

    bf16x8 af[4], bfr[4];
    #pragma unroll
    for (int mi=0; mi<4; mi++) af[mi]  = *(const bf16x8*)&As[wrow+mi*16+lr][lk*8];
    #pragma unroll
    for (int ni=0; ni<4; ni++) bfr[ni] = *(const bf16x8*)&Bs[wcol+ni*16+lr][lk*8];
    #pragma unroll
    for (int mi=0; mi<4; mi++)
      #pragma unroll
      for (int ni=0; ni<4; ni++)
        acc[mi][ni] = __builtin_amdgcn_mfma_f32_16x16x32_bf16(af[mi], bfr[ni], acc[mi][ni], 0,0,0);
  }

  #pragma unroll
  for (int ni=0; ni<4; ni++){
    const int jc = col0 + wcol + ni*16 + lr;
    const float bv = bias[jc];
    #pragma unroll
    for (int mi=0; mi<4; mi++){
      const int tr0 = row0 + wrow + mi*16 + lk*4;
      #pragma unroll
      for (int r=0; r<4; r++)
        XP[(size_t)(tr0+r)*G4 + jc] = f2bf(acc[mi][ni][r] + bv);
    }
  }
}

// ---------------- phase 2: persistent LSTM recurrence (MFMA, 8 waves) ----------------
// EXACTLY R8 except the publish is a memory-side atomic swap (single-variable
// test of write-visibility laziness). 256 WGs x 512 thr. WG g owns h-dims
// [8g,8g+8) = 32 gate rows. Wave w: polls own 512B span of h (plain sc1
// loads), LDS-stages it, 16 MFMAs with LDS-resident pre-swizzled B-frag
// weights, partial write, ONE barrier, wave 0 reduces + parallel-lane cell +
// 4-lane atomic publish.
__global__ __launch_bounds__(NTH, 1) void recur(const unsigned short* __restrict__ XP,
                                                const float* __restrict__ Whh,
                                                unsigned short* __restrict__ Hbuf){
  extern __shared__ char smem[];
  char* hb = smem + HB_OFF;
  const int g = blockIdx.x;
  const int tid = threadIdx.x;
  const int l = tid & 63, w = tid >> 6;

  // ---- stage weights as pre-swizzled MFMA B-fragments (128 KB LDS) ----
  #pragma unroll
  for (int n=0; n<2; n++)
    #pragma unroll
    for (int kt=0; kt<8; kt++){
      const int rr = n*16 + (l & 15);
      const size_t jrow = (size_t)(rr>>3)*HD + (size_t)g*8 + (rr&7);
      const int k = w*256 + kt*32 + (l>>4)*8;
      const float* wp = Whh + jrow*HD + k;
      float4 fa = *(const float4*)wp;
      float4 fb = *(const float4*)(wp + 4);
      uint4 pk;
      pk.x = ((unsigned)f2bf(fa.y)<<16) | f2bf(fa.x);
      pk.y = ((unsigned)f2bf(fa.w)<<16) | f2bf(fa.z);
      pk.z = ((unsigned)f2bf(fb.y)<<16) | f2bf(fb.x);
      pk.w = ((unsigned)f2bf(fb.w)<<16) | f2bf(fb.z);
      *(uint4*)(smem + (size_t)(((w*16 + n*8 + kt)*64 + l)*16)) = pk;
    }
  __syncthreads();

  float c_reg = 0.f;     // cell state (wave 0, lanes 0..7)
  float xpv = 0.f;       // gate preact input (wave 0, lanes 0..31)
  if (w == 0 && l < 32)
    xpv = bf2f(XP[(size_t)(l>>3)*HD + (size_t)g*8 + (l&7)]);

  for (int t=0; t<T_STEPS; ++t){
    // ---- poll own span of h[t-1] (row t; row 0 = zeros), plain sc1 loads ----
    u32x2 hv;
    {
      const unsigned int* hp = (const unsigned int*)(Hbuf + (size_t)t*HD) + w*128 + l*2;
      do { hv = ld2_dev(hp); }
      while (hv[0] == HSENT2 || hv[1] == HSENT2);
    }
    *(u32x2*)(hb + w*512 + l*8) = hv;

    // A-fragments: broadcast h (same addr within each 16-lane group)
    bf16x8 af[8];
    #pragma unroll
    for (int kt=0; kt<8; kt++)
      af[kt] = *(const bf16x8*)(hb + w*512 + kt*64 + (l>>4)*16);

    f32x4 acc0 = (f32x4){0.f,0.f,0.f,0.f};
    f32x4 acc1 = (f32x4){0.f,0.f,0.f,0.f};
    #pragma unroll
    for (int kt=0; kt<8; kt++){
      bf16x8 b0 = *(const bf16x8*)(smem + (size_t)(((w*16 +     kt)*64 + l)*16));
      bf16x8 b1 = *(const bf16x8*)(smem + (size_t)(((w*16 + 8 + kt)*64 + l)*16));
      acc0 = __builtin_amdgcn_mfma_f32_16x16x32_bf16(af[kt], b0, acc0, 0,0,0);
      acc1 = __builtin_amdgcn_mfma_f32_16x16x32_bf16(af[kt], b1, acc1, 0,0,0);
    }
    // partials: [wave][row] layout (conflict-free), parity double-buffered
    float* part = (float*)(smem + P_OFF) + (t&1)*256;
    if (l < 16){
      part[w*32 + l]      = acc0[0];
      part[w*32 + 16 + l] = acc1[0];
    }
    __syncthreads();

    // wave 0: reduce + parallel-lane cell + atomic publish
    if (w == 0){
      __builtin_amdgcn_s_setprio(1);
      float act = 0.f;
      if (l < 32){
        float tot = xpv;
        #pragma unroll
        for (int q=0; q<8; q++) tot += part[q*32 + l];
        const bool isg = ((l>>3) == 2);
        float z = __expf(isg ? -2.f*tot : -tot);
        float s = 1.f/(1.f + z);
        act = isg ? 2.f*s - 1.f : s;    // tanh via sigmoid identity for g-gate
      }
      float fv = __shfl_down(act, 8, 64);
      float gv = __shfl_down(act, 16, 64);
      float ov = __shfl_down(act, 24, 64);
      if (l < 8){
        c_reg = fv*c_reg + act*gv;      // act = i-gate on lanes 0..7
        float e2c = __expf(-2.f*c_reg);
        float th = (1.f - e2c)/(1.f + e2c);
        unsigned v = f2bf(ov*th);
        unsigned p1 = (unsigned)__shfl_xor((int)v, 1, 64);
        unsigned word = (v & 0xFFFFu) | (p1 << 16);   // valid on even lanes
        if ((l & 1) == 0){
          unsigned int* dst = (unsigned int*)(Hbuf + (size_t)(t+1)*HD + (size_t)g*8) + (l>>1);
          pub_atomic(dst, word);
        }
      }
      __builtin_amdgcn_s_setprio(0);
      // preload next step's XP (off critical path)
      if (l < 32){
        const int tn = (t+1 < T_STEPS) ? t+1 : t;
        xpv = bf2f(XP[(size_t)tn*G4 + (size_t)(l>>3)*HD + (size_t)g*8 + (l&7)]);
      }
    }
  }
}

// ---------------- phase 3: y[t] = h_t . W_out + b_out (h is bf16) ----------------
__global__ __launch_bounds__(256) void out_gemv(const unsigned short* __restrict__ Hbuf,
                                                const float* __restrict__ Wout,
                                                const float* __restrict__ bout,
                                                float* __restrict__ y){
  const int t = blockIdx.x;
  const int tid = threadIdx.x;
  u16x8 hv = *(const u16x8*)(Hbuf + (size_t)(t+1)*HD + tid*8);
  float4 w0 = *(const float4*)(Wout + tid*8);
  float4 w1 = *(const float4*)(Wout + tid*8 + 4);
  float s = bf2f(hv[0])*w0.x + bf2f(hv[1])*w0.y + bf2f(hv[2])*w0.z + bf2f(hv[3])*w0.w
          + bf2f(hv[4])*w1.x + bf2f(hv[5])*w1.y + bf2f(hv[6])*w1.z + bf2f(hv[7])*w1.w;
  #pragma unroll
  for (int off=32; off; off>>=1) s += __shfl_xor(s, off, 64);
  __shared__ float ps[4];
  if ((tid & 63) == 0) ps[tid>>6] = s;
  __syncthreads();
  if (tid == 0) y[t] = ps[0]+ps[1]+ps[2]+ps[3] + bout[0];
}

extern "C" void kernel_launch(void* const* d_in, const int* in_sizes, int n_in,
                              void* d_out, int out_size, void* d_ws, size_t ws_size,
                              hipStream_t stream) {
  const float* x    = (const float*)d_in[0];
  const float* Wih  = (const float*)d_in[1];
  const float* Whh  = (const float*)d_in[2];
  const float* b_ih = (const float*)d_in[3];
  const float* b_hh = (const float*)d_in[4];
  const float* Wout = (const float*)d_in[5];
  const float* bout = (const float*)d_in[6];
  float* y = (float*)d_out;

  char* ws = (char*)d_ws;
  unsigned short* XP   = (unsigned short*)(ws);               // 4096*8192*2   = 67108864
  unsigned short* Hbuf = (unsigned short*)(ws + 67108864);    // 4097*2048*2   = 16781312
  float* bias          = (float*)(ws + 83890176);             // 8192*4        = 32768

  init_kernel<<<2048, 256, 0, stream>>>(b_ih, b_hh, bias, (unsigned int*)Hbuf);
  gemm_xp<<<2048, 256, 0, stream>>>(x, Wih, bias, XP);

  hipFuncSetAttribute((const void*)recur,
                      hipFuncAttributeMaxDynamicSharedMemorySize, SMEM_BYTES);
  void* args[] = {(void*)&XP, (void*)&Whh, (void*)&Hbuf};
  hipLaunchCooperativeKernel((void*)recur, dim3(NWG), dim3(NTH), args,
                             SMEM_BYTES, stream);

  out_gemv<<<T_STEPS, 256, 0, stream>>>(Hbuf, Wout, bout, y);
}

// Round 13
// 10266.145 us; speedup vs baseline: 4.7294x; 1.0949x over previous
//
#include <hip/hip_runtime.h>

// FINAL (R13 = revert to R8, the empirical best: 10.28 ms total).
// The recurrence is pinned at the measured device-wide producer->consumer
// visibility RT (~2.4-2.5 us/step x 4096 steps ~= 10 ms), invariant across
// 9 transport/organization variants (R2-R12). See session journal.

#define T_STEPS 4096
#define HD 2048
#define G4 8192
#define NWG 256
#define NTH 512
#define HSENT2 0xFF80FF80u

#define HB_OFF  131072                    // weights 128 KB, then h spans 4 KB
#define P_OFF   (131072 + 4096)           // partials: 2 x (8 waves x 32) f32 = 2 KB
#define SMEM_BYTES (131072 + 4096 + 2048)

typedef __attribute__((ext_vector_type(8))) short bf16x8;
typedef __attribute__((ext_vector_type(4))) float f32x4;
typedef __attribute__((ext_vector_type(8))) unsigned short u16x8;
typedef __attribute__((ext_vector_type(2))) unsigned int u32x2;

static __device__ __forceinline__ unsigned short f2bf(float f){
  union { float f; unsigned int u; } v; v.f = f;
  unsigned int r = (v.u + 0x7fffu + ((v.u >> 16) & 1u)) >> 16;
  return (unsigned short)r;
}
static __device__ __forceinline__ float bf2f(unsigned short s){
  union { unsigned int u; float f; } v; v.u = ((unsigned int)s) << 16;
  return v.f;
}

// DEVICE-scope (sc1) 8B load: bypasses L1/L2, reads the device coherence
// point. Read-only, MSHR-merged across same-line pollers.
static __device__ __forceinline__ u32x2 ld2_dev(const unsigned int* p){
  u32x2 r;
  asm volatile("global_load_dwordx2 %0, %1, off sc1\n\ts_waitcnt vmcnt(0)"
               : "=v"(r) : "v"(p) : "memory");
  return r;
}
// DEVICE-scope write-through 2B store (publish h)
static __device__ __forceinline__ void st2_dev(unsigned short* p, unsigned int v){
  asm volatile("global_store_short %0, %1, off sc1" :: "v"(p), "v"(v) : "memory");
}

// ---------------- init: bias fuse + h0 zeros + sentinel rows (bf16) ----------------
__global__ void init_kernel(const float* __restrict__ b_ih, const float* __restrict__ b_hh,
                            float* __restrict__ bias, unsigned int* __restrict__ Hb32){
  int i = blockIdx.x*blockDim.x + threadIdx.x;
  int stride = gridDim.x*blockDim.x;
  const int HB_U32 = (T_STEPS+1)*HD/2;
  const int NTOT = G4 + HB_U32;
  for (int idx = i; idx < NTOT; idx += stride){
    if (idx < G4) bias[idx] = b_ih[idx] + b_hh[idx];
    else {
      int j = idx - G4;
      Hb32[j] = (j < HD/2) ? 0u : HSENT2;   // row 0 = bf16 zeros, rest sentinel
    }
  }
}

// ---------------- phase 1: XP = x @ W_ih^T + (b_ih+b_hh), bf16 out ----------------
__global__ __launch_bounds__(256) void gemm_xp(const float* __restrict__ X,
                                               const float* __restrict__ W,
                                               const float* __restrict__ bias,
                                               unsigned short* __restrict__ XP){
  __shared__ __align__(16) unsigned short As[128][40];
  __shared__ __align__(16) unsigned short Bs[128][40];
  const int tid = threadIdx.x;
  const int bx = blockIdx.x & 63;
  const int by = blockIdx.x >> 6;
  const int row0 = by*128, col0 = bx*128;
  const int l = tid & 63, w = tid >> 6;
  const int wrow = (w>>1)*64, wcol = (w&1)*64;
  const int lr = l & 15, lk = l >> 4;

  f32x4 acc[4][4];
  #pragma unroll
  for (int mi=0; mi<4; mi++)
    #pragma unroll
    for (int ni=0; ni<4; ni++)
      acc[mi][ni] = (f32x4){0.f,0.f,0.f,0.f};

  const int sr = tid >> 1;
  const int sh = (tid & 1) * 16;
  const float* xb = X + (size_t)(row0+sr)*2048 + sh;
  const float* wb = W + (size_t)(col0+sr)*2048 + sh;

  for (int k0 = 0; k0 < 2048; k0 += 32){
    __syncthreads();
    u16x8 va[2], vb[2];
    #pragma unroll
    for (int q=0; q<2; q++){
      float4 u = *(const float4*)(xb + k0 + q*8);
      float4 v = *(const float4*)(xb + k0 + q*8 + 4);
      u16x8 t;
      t[0]=f2bf(u.x); t[1]=f2bf(u.y); t[2]=f2bf(u.z); t[3]=f2bf(u.w);
      t[4]=f2bf(v.x); t[5]=f2bf(v.y); t[6]=f2bf(v.z); t[7]=f2bf(v.w);
      va[q]=t;
      float4 p = *(const float4*)(wb + k0 + q*8);
      float4 r = *(const float4*)(wb + k0 + q*8 + 4);
      u16x8 s;
      s[0]=f2bf(p.x); s[1]=f2bf(p.y); s[2]=f2bf(p.z); s[3]=f2bf(p.w);
      s[4]=f2bf(r.x); s[5]=f2bf(r.y); s[6]=f2bf(r.z); s[7]=f2bf(r.w);
      vb[q]=s;
    }
    *(u16x8*)&As[sr][sh]   = va[0];
    *(u16x8*)&As[sr][sh+8] = va[1];
    *(u16x8*)&Bs[sr][sh]   = vb[0];
    *(u16x8*)&Bs[sr][sh+8] = vb[1];
    __syncthreads();

    bf16x8 af[4], bfr[4];
    #pragma unroll
    for (int mi=0; mi<4; mi++) af[mi]  = *(const bf16x8*)&As[wrow+mi*16+lr][lk*8];
    #pragma unroll
    for (int ni=0; ni<4; ni++) bfr[ni] = *(const bf16x8*)&Bs[wcol+ni*16+lr][lk*8];
    #pragma unroll
    for (int mi=0; mi<4; mi++)
      #pragma unroll
      for (int ni=0; ni<4; ni++)
        acc[mi][ni] = __builtin_amdgcn_mfma_f32_16x16x32_bf16(af[mi], bfr[ni], acc[mi][ni], 0,0,0);
  }

  #pragma unroll
  for (int ni=0; ni<4; ni++){
    const int jc = col0 + wcol + ni*16 + lr;
    const float bv = bias[jc];
    #pragma unroll
    for (int mi=0; mi<4; mi++){
      const int tr0 = row0 + wrow + mi*16 + lk*4;
      #pragma unroll
      for (int r=0; r<4; r++)
        XP[(size_t)(tr0+r)*G4 + jc] = f2bf(acc[mi][ni][r] + bv);
    }
  }
}

// ---------------- phase 2: persistent LSTM recurrence (MFMA, 8 waves) ----------------
// 256 WGs x 512 thr. WG g owns h-dims [8g,8g+8) = 32 gate rows (rr=gate*8+dd).
// Wave w covers K-slice [w*256,+256): polls ONLY its own 512B span of the h
// row (device-scope loads), writes it to its private LDS region (no barrier:
// same-wave lgkmcnt ordering), 16 MFMAs with LDS-resident pre-swizzled B-frag
// weights, partial write, ONE barrier, wave 0 reduces + parallel-lane cell +
// 8-lane device-scope publish. part[] parity-double-buffered so waves may run
// a step ahead. Sentinel 0xFF80 (bf16 -inf) unreachable since |h|<1.
__global__ __launch_bounds__(NTH, 1) void recur(const unsigned short* __restrict__ XP,
                                                const float* __restrict__ Whh,
                                                unsigned short* __restrict__ Hbuf){
  extern __shared__ char smem[];
  char* hb = smem + HB_OFF;
  const int g = blockIdx.x;
  const int tid = threadIdx.x;
  const int l = tid & 63, w = tid >> 6;

  // ---- stage weights as pre-swizzled MFMA B-fragments (128 KB LDS) ----
  // block idx = w*16 + n*8 + kt; lane l holds B[col=n*16+(l&15)][k=(l>>4)*8..+8]
  #pragma unroll
  for (int n=0; n<2; n++)
    #pragma unroll
    for (int kt=0; kt<8; kt++){
      const int rr = n*16 + (l & 15);
      const size_t jrow = (size_t)(rr>>3)*HD + (size_t)g*8 + (rr&7);
      const int k = w*256 + kt*32 + (l>>4)*8;
      const float* wp = Whh + jrow*HD + k;
      float4 fa = *(const float4*)wp;
      float4 fb = *(const float4*)(wp + 4);
      uint4 pk;
      pk.x = ((unsigned)f2bf(fa.y)<<16) | f2bf(fa.x);
      pk.y = ((unsigned)f2bf(fa.w)<<16) | f2bf(fa.z);
      pk.z = ((unsigned)f2bf(fb.y)<<16) | f2bf(fb.x);
      pk.w = ((unsigned)f2bf(fb.w)<<16) | f2bf(fb.z);
      *(uint4*)(smem + (size_t)(((w*16 + n*8 + kt)*64 + l)*16)) = pk;
    }
  __syncthreads();

  float c_reg = 0.f;     // cell state (wave 0, lanes 0..7)
  float xpv = 0.f;       // gate preact input (wave 0, lanes 0..31)
  if (w == 0 && l < 32)
    xpv = bf2f(XP[(size_t)(l>>3)*HD + (size_t)g*8 + (l&7)]);

  for (int t=0; t<T_STEPS; ++t){
    // ---- poll own span of h[t-1] (row t; row 0 = zeros), device scope ----
    u32x2 hv;
    {
      const unsigned int* hp = (const unsigned int*)(Hbuf + (size_t)t*HD) + w*128 + l*2;
      do { hv = ld2_dev(hp); }
      while (hv[0] == HSENT2 || hv[1] == HSENT2);
    }
    *(u32x2*)(hb + w*512 + l*8) = hv;

    // A-fragments: broadcast h (same addr within each 16-lane group)
    bf16x8 af[8];
    #pragma unroll
    for (int kt=0; kt<8; kt++)
      af[kt] = *(const bf16x8*)(hb + w*512 + kt*64 + (l>>4)*16);

    f32x4 acc0 = (f32x4){0.f,0.f,0.f,0.f};
    f32x4 acc1 = (f32x4){0.f,0.f,0.f,0.f};
    #pragma unroll
    for (int kt=0; kt<8; kt++){
      bf16x8 b0 = *(const bf16x8*)(smem + (size_t)(((w*16 +     kt)*64 + l)*16));
      bf16x8 b1 = *(const bf16x8*)(smem + (size_t)(((w*16 + 8 + kt)*64 + l)*16));
      acc0 = __builtin_amdgcn_mfma_f32_16x16x32_bf16(af[kt], b0, acc0, 0,0,0);
      acc1 = __builtin_amdgcn_mfma_f32_16x16x32_bf16(af[kt], b1, acc1, 0,0,0);
    }
    // partials: [wave][row] layout (conflict-free), parity double-buffered
    float* part = (float*)(smem + P_OFF) + (t&1)*256;
    if (l < 16){
      part[w*32 + l]      = acc0[0];
      part[w*32 + 16 + l] = acc1[0];
    }
    __syncthreads();

    // wave 0: reduce + parallel-lane cell + publish
    if (w == 0){
      __builtin_amdgcn_s_setprio(1);
      float act = 0.f;
      if (l < 32){
        float tot = xpv;
        #pragma unroll
        for (int q=0; q<8; q++) tot += part[q*32 + l];
        const bool isg = ((l>>3) == 2);
        float z = __expf(isg ? -2.f*tot : -tot);
        float s = 1.f/(1.f + z);
        act = isg ? 2.f*s - 1.f : s;    // tanh via sigmoid identity for g-gate
      }
      float fv = __shfl_down(act, 8, 64);
      float gv = __shfl_down(act, 16, 64);
      float ov = __shfl_down(act, 24, 64);
      if (l < 8){
        c_reg = fv*c_reg + act*gv;      // act = i-gate on lanes 0..7
        float e2c = __expf(-2.f*c_reg);
        float th = (1.f - e2c)/(1.f + e2c);
        st2_dev(Hbuf + (size_t)(t+1)*HD + (size_t)g*8 + l, (unsigned)f2bf(ov*th));
      }
      __builtin_amdgcn_s_setprio(0);
      // preload next step's XP (off critical path)
      if (l < 32){
        const int tn = (t+1 < T_STEPS) ? t+1 : t;
        xpv = bf2f(XP[(size_t)tn*G4 + (size_t)(l>>3)*HD + (size_t)g*8 + (l&7)]);
      }
    }
  }
}

// ---------------- phase 3: y[t] = h_t . W_out + b_out (h is bf16) ----------------
__global__ __launch_bounds__(256) void out_gemv(const unsigned short* __restrict__ Hbuf,
                                                const float* __restrict__ Wout,
                                                const float* __restrict__ bout,
                                                float* __restrict__ y){
  const int t = blockIdx.x;
  const int tid = threadIdx.x;
  u16x8 hv = *(const u16x8*)(Hbuf + (size_t)(t+1)*HD + tid*8);
  float4 w0 = *(const float4*)(Wout + tid*8);
  float4 w1 = *(const float4*)(Wout + tid*8 + 4);
  float s = bf2f(hv[0])*w0.x + bf2f(hv[1])*w0.y + bf2f(hv[2])*w0.z + bf2f(hv[3])*w0.w
          + bf2f(hv[4])*w1.x + bf2f(hv[5])*w1.y + bf2f(hv[6])*w1.z + bf2f(hv[7])*w1.w;
  #pragma unroll
  for (int off=32; off; off>>=1) s += __shfl_xor(s, off, 64);
  __shared__ float ps[4];
  if ((tid & 63) == 0) ps[tid>>6] = s;
  __syncthreads();
  if (tid == 0) y[t] = ps[0]+ps[1]+ps[2]+ps[3] + bout[0];
}

extern "C" void kernel_launch(void* const* d_in, const int* in_sizes, int n_in,
                              void* d_out, int out_size, void* d_ws, size_t ws_size,
                              hipStream_t stream) {
  const float* x    = (const float*)d_in[0];
  const float* Wih  = (const float*)d_in[1];
  const float* Whh  = (const float*)d_in[2];
  const float* b_ih = (const float*)d_in[3];
  const float* b_hh = (const float*)d_in[4];
  const float* Wout = (const float*)d_in[5];
  const float* bout = (const float*)d_in[6];
  float* y = (float*)d_out;

  char* ws = (char*)d_ws;
  unsigned short* XP   = (unsigned short*)(ws);               // 4096*8192*2   = 67108864
  unsigned short* Hbuf = (unsigned short*)(ws + 67108864);    // 4097*2048*2   = 16781312
  float* bias          = (float*)(ws + 83890176);             // 8192*4        = 32768

  init_kernel<<<2048, 256, 0, stream>>>(b_ih, b_hh, bias, (unsigned int*)Hbuf);
  gemm_xp<<<2048, 256, 0, stream>>>(x, Wih, bias, XP);

  hipFuncSetAttribute((const void*)recur,
                      hipFuncAttributeMaxDynamicSharedMemorySize, SMEM_BYTES);
  void* args[] = {(void*)&XP, (void*)&Whh, (void*)&Hbuf};
  hipLaunchCooperativeKernel((void*)recur, dim3(NWG), dim3(NTH), args,
                             SMEM_BYTES, stream);

  out_gemv<<<T_STEPS, 256, 0, stream>>>(Hbuf, Wout, bout, y);
}